// Round 9
// baseline (118.168 us; speedup 1.0000x reference)
//
#include <hip/hip_runtime.h>
#include <stdint.h>

#define N_NODES 20000
#define N_EDGES 240000
#define IN_DIM  20
#define OUT_DIM 360   // 20 mlp + 20 sender-sum + 320 tp
#define EPS_F   1e-12f
#define CAP     64    // bucket capacity per node (Binomial mean 12, max ~35)
#define EDGE_BLOCKS ((N_EDGES + 255) / 256)   // 938
#define MLP_BLOCKS  ((N_NODES + 255) / 256)   // 79

typedef _Float16 half8   __attribute__((ext_vector_type(8)));
typedef float    floatx16 __attribute__((ext_vector_type(16)));

__device__ __forceinline__ half8 h8_from_u32(uint32_t u0, uint32_t u1,
                                             uint32_t u2, uint32_t u3) {
    union { uint32_t u[4]; half8 h; } t;
    t.u[0] = u0; t.u[1] = u1; t.u[2] = u2; t.u[3] = u3;
    return t.h;
}

// tail-mask for B fragment: halves j, j+1 valid iff j < t
__device__ __forceinline__ uint32_t maskpair(int t, int j) {
    return (t > j ? 0xFFFFu : 0u) | (t > j + 1 ? 0xFFFF0000u : 0u);
}

// used only in the (normally never-taken) overflow path
__device__ float sh_coeff(int k, float xn, float yn, float zn) {
    const float x2 = xn * xn, y2 = yn * yn, z2 = zn * zn;
    switch (k) {
        case 0:  return 0.28209479177387814f;
        case 1:  return 0.4886025119029199f * yn;
        case 2:  return 0.4886025119029199f * zn;
        case 3:  return 0.4886025119029199f * xn;
        case 4:  return 1.0925484305920792f * xn * yn;
        case 5:  return 1.0925484305920792f * yn * zn;
        case 6:  return 0.31539156525252005f * (3.0f * z2 - 1.0f);
        case 7:  return 1.0925484305920792f * xn * zn;
        case 8:  return 0.5462742152960396f * (x2 - y2);
        case 9:  return 0.5900435899266435f * yn * (3.0f * x2 - y2);
        case 10: return 2.890611442640554f  * xn * yn * zn;
        case 11: return 0.4570457994644658f * yn * (5.0f * z2 - 1.0f);
        case 12: return 0.3731763325901154f * zn * (5.0f * z2 - 3.0f);
        case 13: return 0.4570457994644658f * xn * (5.0f * z2 - 1.0f);
        case 14: return 1.445305721320277f  * zn * (x2 - y2);
        default: return 0.5900435899266435f * xn * (x2 - 3.0f * y2); // k==15
    }
}

// cold, ~never-executed overflow accumulation — OUTLINED so the hot gather
// path's register allocation doesn't pay for it.
__device__ __noinline__ floatx16 ovf_accum(floatx16 acc, int node, int col, int hi,
    const float* __restrict__ x, const float* __restrict__ pos,
    const int* __restrict__ ei, const int* __restrict__ ovf_cnt,
    const int* __restrict__ ovf)
{
    const int mm = *ovf_cnt;
    for (int t2 = 0; t2 < mm; ++t2) {
        const int e = ovf[t2];
        if (ei[N_EDGES + e] != node) continue;   // wave-uniform
        const int row = ei[e];
        const float rx = pos[node * 3 + 0] - pos[row * 3 + 0];
        const float ry = pos[node * 3 + 1] - pos[row * 3 + 1];
        const float rz = pos[node * 3 + 2] - pos[row * 3 + 2];
        const float rinv = rsqrtf(rx * rx + ry * ry + rz * rz + EPS_F);
        float shc;
        if (col < 16)       shc = sh_coeff(col, rx * rinv, ry * rinv, rz * rinv);
        else if (col == 16) shc = 1.0f;
        else                shc = 0.0f;
#pragma unroll
        for (int r = 0; r < 16; ++r) {
            const int rw = ((r & 3) + 8 * (r >> 2)) + 4 * hi;
            if (rw < IN_DIM)
                acc[r] = fmaf(x[(size_t)row * IN_DIM + rw], shc, acc[r]);
        }
    }
    return acc;
}

// ------- fused: bucket build (thread/edge) || node MLP (thread/node) -------
// Edge part: {2 coalesced loads, 1 atomic on compact counts, 1x2B store}.
// counts: one int per node (compact — R3 proved padding/partitioning is a null).
// xpair: u32 xpair[node][20] = {f16 hi(x) (lo), f16 residual (hi)}.
__global__ __launch_bounds__(256) void bucket_mlp(
    const int* __restrict__ ei,
    const float* __restrict__ x,
    const float* __restrict__ Wpre,  const float* __restrict__ bpre,
    const float* __restrict__ Wpost, const float* __restrict__ bpost,
    const float* __restrict__ Wsc,   const float* __restrict__ bsc,
    int* __restrict__ counts,        // [N_NODES]
    int* __restrict__ ovf_cnt,       // [1]
    int* __restrict__ ovf,           // [N_EDGES] (exact)
    uint16_t* __restrict__ bucket16, // [N_NODES * CAP] holds ROW (u16)
    uint32_t* __restrict__ xpair,    // [N_NODES*IN_DIM]
    float* __restrict__ out)
{
    if ((int)blockIdx.x < EDGE_BLOCKS) {
        // ---------------- edge part ----------------
        const int e = (int)(blockIdx.x * 256 + threadIdx.x);
        if (e >= N_EDGES) return;
        const int row = ei[e];
        const int col = ei[N_EDGES + e];
        const int slot = atomicAdd(&counts[col], 1);
        if (slot >= CAP) { ovf[atomicAdd(ovf_cnt, 1)] = e; return; }
        bucket16[col * CAP + slot] = (uint16_t)row;
        return;
    }

    // ---------------- MLP part: thread per node ----------------
    __shared__ float smw[1260];   // 3x400 weights + 60 biases
    for (int t = (int)threadIdx.x; t < 400; t += 256) {
        smw[t]       = Wpre[t];
        smw[400 + t] = Wpost[t];
        smw[800 + t] = Wsc[t];
    }
    if (threadIdx.x < IN_DIM) {
        smw[1200 + threadIdx.x]              = bpre[threadIdx.x];
        smw[1200 + IN_DIM + threadIdx.x]     = bpost[threadIdx.x];
        smw[1200 + 2 * IN_DIM + threadIdx.x] = bsc[threadIdx.x];
    }
    __syncthreads();

    const int i = (int)((blockIdx.x - EDGE_BLOCKS) * 256 + threadIdx.x);
    if (i >= N_NODES) return;

    const float* sWpre  = smw;
    const float* sWpost = smw + 400;
    const float* sWsc   = smw + 800;
    const float* sb     = smw + 1200;

    float xi[IN_DIM], h[IN_DIM];
#pragma unroll
    for (int j = 0; j < IN_DIM; ++j) xi[j] = x[(size_t)i * IN_DIM + j];

    // compensated f16 pair for the gather kernel's MFMA A-operand
#pragma unroll
    for (int j = 0; j < IN_DIM; ++j) {
        const float v = xi[j];
        const _Float16 hh = (_Float16)v;
        const float res = v - (float)hh;
        union { _Float16 f[2]; uint32_t u; } t;
        t.f[0] = hh; t.f[1] = (_Float16)res;
        xpair[(size_t)i * IN_DIM + j] = t.u;
    }

#pragma unroll
    for (int j = 0; j < IN_DIM; ++j) {
        float a = sb[j];
#pragma unroll
        for (int kk = 0; kk < IN_DIM; ++kk) a = fmaf(xi[kk], sWpre[j * IN_DIM + kk], a);
        h[j] = fmaxf(a, 0.0f);
    }
#pragma unroll
    for (int j = 0; j < IN_DIM; ++j) {
        float a = sb[IN_DIM + j] + sb[2 * IN_DIM + j];
#pragma unroll
        for (int kk = 0; kk < IN_DIM; ++kk) {
            a = fmaf(h[kk],  sWpost[j * IN_DIM + kk], a);
            a = fmaf(xi[kk], sWsc[j * IN_DIM + kk],  a);
        }
        out[(size_t)i * OUT_DIM + j] = a;
    }
}

// -------- gather: one wave per node; SH computed in-kernel (1 edge/lane), --------
// -------- LDS transpose, then 16-edge blocks via v_mfma_f32_32x32x16_f16  --------
// C[row=feature i][col=sh comp k] = sum_e s_e[i]*sh_e[k]; col 16 = ones => sender sums.
// Slots are exactly packed 0..cnt-1, lane -> slot identity. ALL random-access
// work (bucket read, pos gather, SH, xpair rows) predicated to valid lanes only.
// C/D layout per m74/m101: col=lane&31, row=(reg&3)+8*(reg>>2)+4*(lane>>5).
__global__ __launch_bounds__(256) void node_gather(
    const float* __restrict__ x,
    const float* __restrict__ pos,
    const int* __restrict__ ei,
    const int* __restrict__ counts,
    const uint16_t* __restrict__ bucket16,
    const uint32_t* __restrict__ xpair,
    const int* __restrict__ ovf_cnt,
    const int* __restrict__ ovf,
    float* __restrict__ out)
{
    __shared__ uint16_t shls[4][64][16];   // 8 KB: per-wave SH transpose buffer

    const int lane  = (int)(threadIdx.x & 63);
    const int w     = (int)(threadIdx.x >> 6);
    const int node  = __builtin_amdgcn_readfirstlane(
        (int)((blockIdx.x * blockDim.x + threadIdx.x) >> 6));   // grid exact
    const int col   = lane & 31;
    const int hi    = lane >> 5;
    const int khalf = hi * 8;
    const int rowc  = min(col, IN_DIM - 1);

    const int cnt_raw = __builtin_amdgcn_readfirstlane(counts[node]);
    const int cnt = min(cnt_raw, CAP);

    // ---- per-lane edge (ONLY valid lanes issue memory traffic) ----
    int rl = 0;
    if (lane < cnt) {
        rl = (int)bucket16[node * CAP + lane];   // always written this iter
        const float rx = pos[node * 3 + 0] - pos[rl * 3 + 0];
        const float ry = pos[node * 3 + 1] - pos[rl * 3 + 1];
        const float rz = pos[node * 3 + 2] - pos[rl * 3 + 2];
        const float rinv = rsqrtf(rx * rx + ry * ry + rz * rz + EPS_F);
        const float xx = rx * rinv, yy = ry * rinv, zz = rz * rinv;
        const float x2 = xx * xx, y2 = yy * yy, z2 = zz * zz;

        const float sh0  = 0.28209479177387814f;
        const float sh1  = 0.4886025119029199f * yy;
        const float sh2  = 0.4886025119029199f * zz;
        const float sh3  = 0.4886025119029199f * xx;
        const float sh4  = 1.0925484305920792f * xx * yy;
        const float sh5  = 1.0925484305920792f * yy * zz;
        const float sh6  = 0.31539156525252005f * (3.0f * z2 - 1.0f);
        const float sh7  = 1.0925484305920792f * xx * zz;
        const float sh8  = 0.5462742152960396f * (x2 - y2);
        const float sh9  = 0.5900435899266435f * yy * (3.0f * x2 - y2);
        const float sh10 = 2.890611442640554f  * xx * yy * zz;
        const float sh11 = 0.4570457994644658f * yy * (5.0f * z2 - 1.0f);
        const float sh12 = 0.3731763325901154f * zz * (5.0f * z2 - 3.0f);
        const float sh13 = 0.4570457994644658f * xx * (5.0f * z2 - 1.0f);
        const float sh14 = 1.445305721320277f  * zz * (x2 - y2);
        const float sh15 = 0.5900435899266435f * xx * (x2 - 3.0f * y2);

        const half8 v0 = { (_Float16)sh0,  (_Float16)sh1,  (_Float16)sh2,  (_Float16)sh3,
                           (_Float16)sh4,  (_Float16)sh5,  (_Float16)sh6,  (_Float16)sh7 };
        const half8 v1 = { (_Float16)sh8,  (_Float16)sh9,  (_Float16)sh10, (_Float16)sh11,
                           (_Float16)sh12, (_Float16)sh13, (_Float16)sh14, (_Float16)sh15 };
        half8* wp = (half8*)&shls[w][lane][0];
        wp[0] = v0;
        wp[1] = v1;
    }
    // no __syncthreads(): shls[w] is wave-private; LDS is wave-synchronous.
    // Rows >= cnt stay uninitialized — they only feed tail-masked B halves.

    floatx16 acc = {0,0,0,0,0,0,0,0,0,0,0,0,0,0,0,0};

    if (cnt > 0) {
        const int nb = (cnt + 15) >> 4;
        for (int b = 0; b < nb; ++b) {
            const int sbase = 16 * b + khalf;

            int rr[8];
#pragma unroll
            for (int j = 0; j < 8; ++j)
                rr[j] = __shfl(rl, sbase + j, 64);

            // A-rows 20..31 never reach the output; skip their loads too.
            uint32_t ee[8];
#pragma unroll
            for (int j = 0; j < 8; ++j)
                ee[j] = (sbase + j < cnt && col < IN_DIM)
                      ? xpair[(size_t)rr[j] * IN_DIM + rowc] : 0u;

            // B source: LDS transpose read — comp 'col' of edges sbase+0..7
            uint32_t B0, B1, B2, B3;
            if (col < 16) {
                const uint32_t h0 = shls[w][sbase + 0][col];
                const uint32_t h1 = shls[w][sbase + 1][col];
                const uint32_t h2 = shls[w][sbase + 2][col];
                const uint32_t h3 = shls[w][sbase + 3][col];
                const uint32_t h4 = shls[w][sbase + 4][col];
                const uint32_t h5 = shls[w][sbase + 5][col];
                const uint32_t h6 = shls[w][sbase + 6][col];
                const uint32_t h7 = shls[w][sbase + 7][col];
                B0 = h0 | (h1 << 16);
                B1 = h2 | (h3 << 16);
                B2 = h4 | (h5 << 16);
                B3 = h6 | (h7 << 16);
            } else if (col == 16) {          // ones column -> sender sums
                B0 = B1 = B2 = B3 = 0x3C003C00u;
            } else {
                B0 = B1 = B2 = B3 = 0u;
            }
            const int rem = cnt - 16 * b;
            if (rem < 16) {                  // zero invalid edges (bit-level, NaN-safe)
                const int t = rem - khalf;
                B0 &= maskpair(t, 0);
                B1 &= maskpair(t, 2);
                B2 &= maskpair(t, 4);
                B3 &= maskpair(t, 6);
            }

            // A fragments: hi halves -> A1, residual halves -> A2
            uint32_t a1u[4], a2u[4];
#pragma unroll
            for (int pq = 0; pq < 4; ++pq) {
                a1u[pq] = (ee[2 * pq] & 0xFFFFu)  | (ee[2 * pq + 1] << 16);
                a2u[pq] = (ee[2 * pq] >> 16)      | (ee[2 * pq + 1] & 0xFFFF0000u);
            }

            const half8 hb  = h8_from_u32(B0, B1, B2, B3);
            const half8 ha1 = h8_from_u32(a1u[0], a1u[1], a1u[2], a1u[3]);
            const half8 ha2 = h8_from_u32(a2u[0], a2u[1], a2u[2], a2u[3]);
            acc = __builtin_amdgcn_mfma_f32_32x32x16_f16(ha1, hb, acc, 0, 0, 0);
            acc = __builtin_amdgcn_mfma_f32_32x32x16_f16(ha2, hb, acc, 0, 0, 0);
        }
    }

    // exact overflow fallback (in-degree > CAP; ~never taken; outlined/cold)
    if (cnt_raw > CAP)
        acc = ovf_accum(acc, node, col, hi, x, pos, ei, ovf_cnt, ovf);

    // epilogue: C -> out (also writes zeros for cnt==0 nodes)
    float* orow = out + (size_t)node * OUT_DIM;
    if (col < 16) {
#pragma unroll
        for (int r = 0; r < 16; ++r) {
            const int rw = ((r & 3) + 8 * (r >> 2)) + 4 * hi;
            if (rw < IN_DIM) orow[2 * IN_DIM + rw * 16 + col] = acc[r];  // tp block
        }
    } else if (col == 16) {
#pragma unroll
        for (int r = 0; r < 16; ++r) {
            const int rw = ((r & 3) + 8 * (r >> 2)) + 4 * hi;
            if (rw < IN_DIM) orow[IN_DIM + rw] = acc[r];                 // sender sums
        }
    }
}

extern "C" void kernel_launch(void* const* d_in, const int* in_sizes, int n_in,
                              void* d_out, int out_size, void* d_ws, size_t ws_size,
                              hipStream_t stream)
{
    const float* x     = (const float*)d_in[0];
    const float* pos   = (const float*)d_in[1];
    const int*   ei    = (const int*)d_in[2];
    const float* Wpre  = (const float*)d_in[3];
    const float* bpre  = (const float*)d_in[4];
    const float* Wpost = (const float*)d_in[5];
    const float* bpost = (const float*)d_in[6];
    const float* Wsc   = (const float*)d_in[7];
    const float* bsc   = (const float*)d_in[8];
    float* out = (float*)d_out;

    // ws layout:
    //   bucket16: N*CAP*2B =  2,560,000
    //   xpair   : N*20*4B  =  1,600,000
    //   counts  : N*4B     =     80,000
    //   ovf_cnt : 4
    //   ovf     : E*4B     =    960,000
    char* wp = (char*)d_ws;
    uint16_t* bucket16 = (uint16_t*)wp;   wp += (size_t)N_NODES * CAP * 2;
    uint32_t* xpair    = (uint32_t*)wp;   wp += (size_t)N_NODES * IN_DIM * 4;
    int*      counts   = (int*)wp;        wp += (size_t)N_NODES * 4;
    int*      ovf_cnt  = (int*)wp;        wp += 4;
    int*      ovf      = (int*)wp;

    // zero counts + ovf_cnt (adjacent) — 80 KB only
    hipMemsetAsync(counts, 0, (size_t)(N_NODES + 1) * sizeof(int), stream);

    bucket_mlp<<<EDGE_BLOCKS + MLP_BLOCKS, 256, 0, stream>>>(
        ei, x, Wpre, bpre, Wpost, bpost, Wsc, bsc,
        counts, ovf_cnt, ovf, bucket16, xpair, out);

    node_gather<<<(N_NODES * 64) / 256, 256, 0, stream>>>(   // exactly 5000 blocks
        x, pos, ei, counts, bucket16, xpair, ovf_cnt, ovf, out);
}

// Round 10
// 116.491 us; speedup vs baseline: 1.0144x; 1.0144x over previous
//
#include <hip/hip_runtime.h>
#include <stdint.h>

#define N_NODES 20000
#define N_EDGES 240000
#define IN_DIM  20
#define OUT_DIM 360   // 20 mlp + 20 sender-sum + 320 tp
#define EPS_F   1e-12f
#define NPART   8     // counter partitions (~XCDs via blockIdx&7)
#define CAP_P   16    // slots per (node, partition); per-part count ~Poisson(1.5)
#define SLOTS   (NPART * CAP_P)   // 128 slots per node
#define EDGE_BLOCKS ((N_EDGES + 255) / 256)   // 938
#define MLP_BLOCKS  ((N_NODES + 255) / 256)   // 79

typedef _Float16 half8   __attribute__((ext_vector_type(8)));
typedef float    floatx16 __attribute__((ext_vector_type(16)));

__device__ __forceinline__ half8 h8_from_u32(uint32_t u0, uint32_t u1,
                                             uint32_t u2, uint32_t u3) {
    union { uint32_t u[4]; half8 h; } t;
    t.u[0] = u0; t.u[1] = u1; t.u[2] = u2; t.u[3] = u3;
    return t.h;
}

// tail-mask for B fragment: halves j, j+1 valid iff j < t
__device__ __forceinline__ uint32_t maskpair(int t, int j) {
    return (t > j ? 0xFFFFu : 0u) | (t > j + 1 ? 0xFFFF0000u : 0u);
}

// used only in the (normally never-taken) overflow path
__device__ float sh_coeff(int k, float xn, float yn, float zn) {
    const float x2 = xn * xn, y2 = yn * yn, z2 = zn * zn;
    switch (k) {
        case 0:  return 0.28209479177387814f;
        case 1:  return 0.4886025119029199f * yn;
        case 2:  return 0.4886025119029199f * zn;
        case 3:  return 0.4886025119029199f * xn;
        case 4:  return 1.0925484305920792f * xn * yn;
        case 5:  return 1.0925484305920792f * yn * zn;
        case 6:  return 0.31539156525252005f * (3.0f * z2 - 1.0f);
        case 7:  return 1.0925484305920792f * xn * zn;
        case 8:  return 0.5462742152960396f * (x2 - y2);
        case 9:  return 0.5900435899266435f * yn * (3.0f * x2 - y2);
        case 10: return 2.890611442640554f  * xn * yn * zn;
        case 11: return 0.4570457994644658f * yn * (5.0f * z2 - 1.0f);
        case 12: return 0.3731763325901154f * zn * (5.0f * z2 - 3.0f);
        case 13: return 0.4570457994644658f * xn * (5.0f * z2 - 1.0f);
        case 14: return 1.445305721320277f  * zn * (x2 - y2);
        default: return 0.5900435899266435f * xn * (x2 - 3.0f * y2); // k==15
    }
}

// cold, ~never-executed overflow accumulation — OUTLINED so the hot gather
// path's register allocation doesn't pay for it.
__device__ __noinline__ floatx16 ovf_accum(floatx16 acc, int node, int col, int hi,
    const float* __restrict__ x, const float* __restrict__ pos,
    const int* __restrict__ ei, const int* __restrict__ ovf_cnt,
    const int* __restrict__ ovf)
{
    const int mm = *ovf_cnt;
    for (int t2 = 0; t2 < mm; ++t2) {
        const int e = ovf[t2];
        if (ei[N_EDGES + e] != node) continue;   // wave-uniform
        const int row = ei[e];
        const float rx = pos[node * 3 + 0] - pos[row * 3 + 0];
        const float ry = pos[node * 3 + 1] - pos[row * 3 + 1];
        const float rz = pos[node * 3 + 2] - pos[row * 3 + 2];
        const float rinv = rsqrtf(rx * rx + ry * ry + rz * rz + EPS_F);
        float shc;
        if (col < 16)       shc = sh_coeff(col, rx * rinv, ry * rinv, rz * rinv);
        else if (col == 16) shc = 1.0f;
        else                shc = 0.0f;
#pragma unroll
        for (int r = 0; r < 16; ++r) {
            const int rw = ((r & 3) + 8 * (r >> 2)) + 4 * hi;
            if (rw < IN_DIM)
                acc[r] = fmaf(x[(size_t)row * IN_DIM + rw], shc, acc[r]);
        }
    }
    return acc;
}

// ------- fused: bucket build (thread/edge) || node MLP (thread/node) -------
// Edge part: {2 coalesced loads, 1 atomic, 1x2B store}. Counters PADDED (one per
// 64B line) + PARTITIONED by blockIdx&7 — measured ~6us faster than compact (R7 vs R9).
// xpair: u32 xpair[node][20] = {f16 hi(x) (lo), f16 residual (hi)}.
__global__ __launch_bounds__(256) void bucket_mlp(
    const int* __restrict__ ei,
    const float* __restrict__ x,
    const float* __restrict__ Wpre,  const float* __restrict__ bpre,
    const float* __restrict__ Wpost, const float* __restrict__ bpost,
    const float* __restrict__ Wsc,   const float* __restrict__ bsc,
    int* __restrict__ cnt_pad,       // [NPART * N_NODES * 16]
    int* __restrict__ ovf_cnt,       // [1]
    int* __restrict__ ovf,           // [N_EDGES] (exact)
    uint16_t* __restrict__ bucket16, // [N_NODES * SLOTS] holds ROW (u16)
    uint32_t* __restrict__ xpair,    // [N_NODES*IN_DIM]
    float* __restrict__ out)
{
    if ((int)blockIdx.x < EDGE_BLOCKS) {
        // ---------------- edge part ----------------
        const int e = (int)(blockIdx.x * 256 + threadIdx.x);
        if (e >= N_EDGES) return;
        const int p = (int)(blockIdx.x & (NPART - 1));
        const int row = ei[e];
        const int col = ei[N_EDGES + e];
        const int slot = atomicAdd(&cnt_pad[((size_t)(p * N_NODES + col)) << 4], 1);
        if (slot >= CAP_P) { ovf[atomicAdd(ovf_cnt, 1)] = e; return; }
        bucket16[col * SLOTS + (p << 4) + slot] = (uint16_t)row;
        return;
    }

    // ---------------- MLP part: thread per node ----------------
    __shared__ float smw[1260];   // 3x400 weights + 60 biases
    for (int t = (int)threadIdx.x; t < 400; t += 256) {
        smw[t]       = Wpre[t];
        smw[400 + t] = Wpost[t];
        smw[800 + t] = Wsc[t];
    }
    if (threadIdx.x < IN_DIM) {
        smw[1200 + threadIdx.x]              = bpre[threadIdx.x];
        smw[1200 + IN_DIM + threadIdx.x]     = bpost[threadIdx.x];
        smw[1200 + 2 * IN_DIM + threadIdx.x] = bsc[threadIdx.x];
    }
    __syncthreads();

    const int i = (int)((blockIdx.x - EDGE_BLOCKS) * 256 + threadIdx.x);
    if (i >= N_NODES) return;

    const float* sWpre  = smw;
    const float* sWpost = smw + 400;
    const float* sWsc   = smw + 800;
    const float* sb     = smw + 1200;

    float xi[IN_DIM], h[IN_DIM];
#pragma unroll
    for (int j = 0; j < IN_DIM; ++j) xi[j] = x[(size_t)i * IN_DIM + j];

    // compensated f16 pair for the gather kernel's MFMA A-operand
#pragma unroll
    for (int j = 0; j < IN_DIM; ++j) {
        const float v = xi[j];
        const _Float16 hh = (_Float16)v;
        const float res = v - (float)hh;
        union { _Float16 f[2]; uint32_t u; } t;
        t.f[0] = hh; t.f[1] = (_Float16)res;
        xpair[(size_t)i * IN_DIM + j] = t.u;
    }

#pragma unroll
    for (int j = 0; j < IN_DIM; ++j) {
        float a = sb[j];
#pragma unroll
        for (int kk = 0; kk < IN_DIM; ++kk) a = fmaf(xi[kk], sWpre[j * IN_DIM + kk], a);
        h[j] = fmaxf(a, 0.0f);
    }
#pragma unroll
    for (int j = 0; j < IN_DIM; ++j) {
        float a = sb[IN_DIM + j] + sb[2 * IN_DIM + j];
#pragma unroll
        for (int kk = 0; kk < IN_DIM; ++kk) {
            a = fmaf(h[kk],  sWpost[j * IN_DIM + kk], a);
            a = fmaf(xi[kk], sWsc[j * IN_DIM + kk],  a);
        }
        out[(size_t)i * OUT_DIM + j] = a;
    }
}

// -------- gather: one wave per node; SH computed in-kernel (1 edge/lane), --------
// -------- LDS transpose, then 16-edge blocks via v_mfma_f32_32x32x16_f16  --------
// C[row=feature i][col=sh comp k] = sum_e s_e[i]*sh_e[k]; col 16 = ones => sender sums.
// Lane -> packed slot m = 16*p + s via in-register prefix over the 8 partition
// counts. ALL random-access work (bucket read, pos gather, SH, xpair rows)
// predicated to valid lanes (R9's measured ~6us win).
// C/D layout per m74/m101: col=lane&31, row=(reg&3)+8*(reg>>2)+4*(lane>>5).
__global__ __launch_bounds__(256) void node_gather(
    const float* __restrict__ x,
    const float* __restrict__ pos,
    const int* __restrict__ ei,
    const int* __restrict__ cnt_pad,
    const uint16_t* __restrict__ bucket16,
    const uint32_t* __restrict__ xpair,
    const int* __restrict__ ovf_cnt,
    const int* __restrict__ ovf,
    float* __restrict__ out)
{
    __shared__ uint16_t shls[4][64][16];   // 8 KB: per-wave SH transpose buffer

    const int lane  = (int)(threadIdx.x & 63);
    const int w     = (int)(threadIdx.x >> 6);
    const int node  = __builtin_amdgcn_readfirstlane(
        (int)((blockIdx.x * blockDim.x + threadIdx.x) >> 6));   // grid exact
    const int col   = lane & 31;
    const int hi    = lane >> 5;
    const int khalf = hi * 8;
    const int rowc  = min(col, IN_DIM - 1);

    // ---- read 8 partition counts, build prefix + lane->slot mapping ----
    int ovf_any = 0;
    int c[NPART];
#pragma unroll
    for (int q = 0; q < NPART; ++q) {
        const int cr = __builtin_amdgcn_readfirstlane(
            cnt_pad[((size_t)(q * N_NODES + node)) << 4]);
        ovf_any |= (cr > CAP_P);
        c[q] = min(cr, CAP_P);
    }
    int pre = 0, pp = 0, base = 0;
#pragma unroll
    for (int q = 0; q < NPART; ++q) {
        if (q >= 1) {
            const int ge = (lane >= pre) ? 1 : 0;
            pp  += ge;
            base = ge ? pre : base;
        }
        pre += c[q];
    }
    const int cnt = min(pre, 64);                  // in-degree <= 64 in practice
    const int s  = min(lane - base, CAP_P - 1);
    const int m  = (pp << 4) + s;                  // packed slot for edge-index 'lane'

    // ---- per-lane edge (ONLY valid lanes issue memory traffic) ----
    int rl = 0;
    if (lane < cnt) {
        rl = (int)bucket16[node * SLOTS + m];   // valid lanes map to written slots
        const float rx = pos[node * 3 + 0] - pos[rl * 3 + 0];
        const float ry = pos[node * 3 + 1] - pos[rl * 3 + 1];
        const float rz = pos[node * 3 + 2] - pos[rl * 3 + 2];
        const float rinv = rsqrtf(rx * rx + ry * ry + rz * rz + EPS_F);
        const float xx = rx * rinv, yy = ry * rinv, zz = rz * rinv;
        const float x2 = xx * xx, y2 = yy * yy, z2 = zz * zz;

        const float sh0  = 0.28209479177387814f;
        const float sh1  = 0.4886025119029199f * yy;
        const float sh2  = 0.4886025119029199f * zz;
        const float sh3  = 0.4886025119029199f * xx;
        const float sh4  = 1.0925484305920792f * xx * yy;
        const float sh5  = 1.0925484305920792f * yy * zz;
        const float sh6  = 0.31539156525252005f * (3.0f * z2 - 1.0f);
        const float sh7  = 1.0925484305920792f * xx * zz;
        const float sh8  = 0.5462742152960396f * (x2 - y2);
        const float sh9  = 0.5900435899266435f * yy * (3.0f * x2 - y2);
        const float sh10 = 2.890611442640554f  * xx * yy * zz;
        const float sh11 = 0.4570457994644658f * yy * (5.0f * z2 - 1.0f);
        const float sh12 = 0.3731763325901154f * zz * (5.0f * z2 - 3.0f);
        const float sh13 = 0.4570457994644658f * xx * (5.0f * z2 - 1.0f);
        const float sh14 = 1.445305721320277f  * zz * (x2 - y2);
        const float sh15 = 0.5900435899266435f * xx * (x2 - 3.0f * y2);

        const half8 v0 = { (_Float16)sh0,  (_Float16)sh1,  (_Float16)sh2,  (_Float16)sh3,
                           (_Float16)sh4,  (_Float16)sh5,  (_Float16)sh6,  (_Float16)sh7 };
        const half8 v1 = { (_Float16)sh8,  (_Float16)sh9,  (_Float16)sh10, (_Float16)sh11,
                           (_Float16)sh12, (_Float16)sh13, (_Float16)sh14, (_Float16)sh15 };
        half8* wp = (half8*)&shls[w][lane][0];
        wp[0] = v0;
        wp[1] = v1;
    }
    // no __syncthreads(): shls[w] is wave-private; LDS is wave-synchronous.
    // Rows >= cnt stay uninitialized — they only feed tail-masked B halves.

    floatx16 acc = {0,0,0,0,0,0,0,0,0,0,0,0,0,0,0,0};

    if (cnt > 0) {
        const int nb = (cnt + 15) >> 4;
        for (int b = 0; b < nb; ++b) {
            const int sbase = 16 * b + khalf;

            int rr[8];
#pragma unroll
            for (int j = 0; j < 8; ++j)
                rr[j] = __shfl(rl, sbase + j, 64);

            // A-rows 20..31 never reach the output; skip their loads too.
            uint32_t ee[8];
#pragma unroll
            for (int j = 0; j < 8; ++j)
                ee[j] = (sbase + j < cnt && col < IN_DIM)
                      ? xpair[(size_t)rr[j] * IN_DIM + rowc] : 0u;

            // B source: LDS transpose read — comp 'col' of edges sbase+0..7
            uint32_t B0, B1, B2, B3;
            if (col < 16) {
                const uint32_t h0 = shls[w][sbase + 0][col];
                const uint32_t h1 = shls[w][sbase + 1][col];
                const uint32_t h2 = shls[w][sbase + 2][col];
                const uint32_t h3 = shls[w][sbase + 3][col];
                const uint32_t h4 = shls[w][sbase + 4][col];
                const uint32_t h5 = shls[w][sbase + 5][col];
                const uint32_t h6 = shls[w][sbase + 6][col];
                const uint32_t h7 = shls[w][sbase + 7][col];
                B0 = h0 | (h1 << 16);
                B1 = h2 | (h3 << 16);
                B2 = h4 | (h5 << 16);
                B3 = h6 | (h7 << 16);
            } else if (col == 16) {          // ones column -> sender sums
                B0 = B1 = B2 = B3 = 0x3C003C00u;
            } else {
                B0 = B1 = B2 = B3 = 0u;
            }
            const int rem = cnt - 16 * b;
            if (rem < 16) {                  // zero invalid edges (bit-level, NaN-safe)
                const int t = rem - khalf;
                B0 &= maskpair(t, 0);
                B1 &= maskpair(t, 2);
                B2 &= maskpair(t, 4);
                B3 &= maskpair(t, 6);
            }

            // A fragments: hi halves -> A1, residual halves -> A2
            uint32_t a1u[4], a2u[4];
#pragma unroll
            for (int pq = 0; pq < 4; ++pq) {
                a1u[pq] = (ee[2 * pq] & 0xFFFFu)  | (ee[2 * pq + 1] << 16);
                a2u[pq] = (ee[2 * pq] >> 16)      | (ee[2 * pq + 1] & 0xFFFF0000u);
            }

            const half8 hb  = h8_from_u32(B0, B1, B2, B3);
            const half8 ha1 = h8_from_u32(a1u[0], a1u[1], a1u[2], a1u[3]);
            const half8 ha2 = h8_from_u32(a2u[0], a2u[1], a2u[2], a2u[3]);
            acc = __builtin_amdgcn_mfma_f32_32x32x16_f16(ha1, hb, acc, 0, 0, 0);
            acc = __builtin_amdgcn_mfma_f32_32x32x16_f16(ha2, hb, acc, 0, 0, 0);
        }
    }

    // exact overflow fallback (any partition count > CAP_P; ~never taken; cold)
    if (ovf_any)
        acc = ovf_accum(acc, node, col, hi, x, pos, ei, ovf_cnt, ovf);

    // epilogue: C -> out (also writes zeros for cnt==0 nodes)
    float* orow = out + (size_t)node * OUT_DIM;
    if (col < 16) {
#pragma unroll
        for (int r = 0; r < 16; ++r) {
            const int rw = ((r & 3) + 8 * (r >> 2)) + 4 * hi;
            if (rw < IN_DIM) orow[2 * IN_DIM + rw * 16 + col] = acc[r];  // tp block
        }
    } else if (col == 16) {
#pragma unroll
        for (int r = 0; r < 16; ++r) {
            const int rw = ((r & 3) + 8 * (r >> 2)) + 4 * hi;
            if (rw < IN_DIM) orow[IN_DIM + rw] = acc[r];                 // sender sums
        }
    }
}

extern "C" void kernel_launch(void* const* d_in, const int* in_sizes, int n_in,
                              void* d_out, int out_size, void* d_ws, size_t ws_size,
                              hipStream_t stream)
{
    const float* x     = (const float*)d_in[0];
    const float* pos   = (const float*)d_in[1];
    const int*   ei    = (const int*)d_in[2];
    const float* Wpre  = (const float*)d_in[3];
    const float* bpre  = (const float*)d_in[4];
    const float* Wpost = (const float*)d_in[5];
    const float* bpost = (const float*)d_in[6];
    const float* Wsc   = (const float*)d_in[7];
    const float* bsc   = (const float*)d_in[8];
    float* out = (float*)d_out;

    // ws layout:
    //   bucket16: N*SLOTS*2B =  5,120,000
    //   xpair   : N*20*4B    =  1,600,000
    //   cnt_pad : 8*N*64B    = 10,240,000
    //   ovf_cnt : 4
    //   ovf     : E*4B       =    960,000
    char* wp = (char*)d_ws;
    uint16_t* bucket16 = (uint16_t*)wp;   wp += (size_t)N_NODES * SLOTS * 2;
    uint32_t* xpair    = (uint32_t*)wp;   wp += (size_t)N_NODES * IN_DIM * 4;
    int*      cnt_pad  = (int*)wp;        wp += (size_t)NPART * N_NODES * 64;
    int*      ovf_cnt  = (int*)wp;        wp += 4;
    int*      ovf      = (int*)wp;

    // zero counters (+ ovf_cnt, adjacent)
    hipMemsetAsync(cnt_pad, 0, (size_t)NPART * N_NODES * 64 + 4, stream);

    bucket_mlp<<<EDGE_BLOCKS + MLP_BLOCKS, 256, 0, stream>>>(
        ei, x, Wpre, bpre, Wpost, bpost, Wsc, bsc,
        cnt_pad, ovf_cnt, ovf, bucket16, xpair, out);

    node_gather<<<(N_NODES * 64) / 256, 256, 0, stream>>>(   // exactly 5000 blocks
        x, pos, ei, cnt_pad, bucket16, xpair, ovf_cnt, ovf, out);
}

// Round 11
// 114.967 us; speedup vs baseline: 1.0278x; 1.0133x over previous
//
#include <hip/hip_runtime.h>
#include <stdint.h>

#define N_NODES 20000
#define N_EDGES 240000
#define IN_DIM  20
#define OUT_DIM 360   // 20 mlp + 20 sender-sum + 320 tp
#define EPS_F   1e-12f
#define NPART   8     // counter partitions (~XCDs via blockIdx&7)
#define CAP_P   16    // slots per (node, partition); per-part count ~Poisson(1.5)
#define SLOTS   (NPART * CAP_P)   // 128 slots per node
#define CPAD    4     // counter stride in ints (16B): 4 same-partition counters/64B line
#define EDGE_BLOCKS ((N_EDGES + 255) / 256)   // 938
#define MLP_BLOCKS  ((N_NODES + 255) / 256)   // 79

typedef _Float16 half8   __attribute__((ext_vector_type(8)));
typedef float    floatx16 __attribute__((ext_vector_type(16)));

__device__ __forceinline__ half8 h8_from_u32(uint32_t u0, uint32_t u1,
                                             uint32_t u2, uint32_t u3) {
    union { uint32_t u[4]; half8 h; } t;
    t.u[0] = u0; t.u[1] = u1; t.u[2] = u2; t.u[3] = u3;
    return t.h;
}

// tail-mask for B fragment: halves j, j+1 valid iff j < t
__device__ __forceinline__ uint32_t maskpair(int t, int j) {
    return (t > j ? 0xFFFFu : 0u) | (t > j + 1 ? 0xFFFF0000u : 0u);
}

// used only in the (normally never-taken) overflow path
__device__ float sh_coeff(int k, float xn, float yn, float zn) {
    const float x2 = xn * xn, y2 = yn * yn, z2 = zn * zn;
    switch (k) {
        case 0:  return 0.28209479177387814f;
        case 1:  return 0.4886025119029199f * yn;
        case 2:  return 0.4886025119029199f * zn;
        case 3:  return 0.4886025119029199f * xn;
        case 4:  return 1.0925484305920792f * xn * yn;
        case 5:  return 1.0925484305920792f * yn * zn;
        case 6:  return 0.31539156525252005f * (3.0f * z2 - 1.0f);
        case 7:  return 1.0925484305920792f * xn * zn;
        case 8:  return 0.5462742152960396f * (x2 - y2);
        case 9:  return 0.5900435899266435f * yn * (3.0f * x2 - y2);
        case 10: return 2.890611442640554f  * xn * yn * zn;
        case 11: return 0.4570457994644658f * yn * (5.0f * z2 - 1.0f);
        case 12: return 0.3731763325901154f * zn * (5.0f * z2 - 3.0f);
        case 13: return 0.4570457994644658f * xn * (5.0f * z2 - 1.0f);
        case 14: return 1.445305721320277f  * zn * (x2 - y2);
        default: return 0.5900435899266435f * xn * (x2 - 3.0f * y2); // k==15
    }
}

// cold, ~never-executed overflow accumulation — OUTLINED so the hot gather
// path's register allocation doesn't pay for it.
__device__ __noinline__ floatx16 ovf_accum(floatx16 acc, int node, int col, int hi,
    const float* __restrict__ x, const float* __restrict__ pos,
    const int* __restrict__ ei, const int* __restrict__ ovf_cnt,
    const int* __restrict__ ovf)
{
    const int mm = *ovf_cnt;
    for (int t2 = 0; t2 < mm; ++t2) {
        const int e = ovf[t2];
        if (ei[N_EDGES + e] != node) continue;   // wave-uniform
        const int row = ei[e];
        const float rx = pos[node * 3 + 0] - pos[row * 3 + 0];
        const float ry = pos[node * 3 + 1] - pos[row * 3 + 1];
        const float rz = pos[node * 3 + 2] - pos[row * 3 + 2];
        const float rinv = rsqrtf(rx * rx + ry * ry + rz * rz + EPS_F);
        float shc;
        if (col < 16)       shc = sh_coeff(col, rx * rinv, ry * rinv, rz * rinv);
        else if (col == 16) shc = 1.0f;
        else                shc = 0.0f;
#pragma unroll
        for (int r = 0; r < 16; ++r) {
            const int rw = ((r & 3) + 8 * (r >> 2)) + 4 * hi;
            if (rw < IN_DIM)
                acc[r] = fmaf(x[(size_t)row * IN_DIM + rw], shc, acc[r]);
        }
    }
    return acc;
}

// ------- fused: node MLP (blocks 0..78, FIRST so it hides under the atomic flood)
// -------        || bucket build (blocks 79..1016, thread/edge) -------
// Edge part: {2 coalesced loads, 1 atomic, 1x2B store}. Counters at 16B stride,
// partitioned by blockIdx&7: a 64B line holds 4 SAME-partition counters (20000%4==0,
// lines never span partitions) -> no cross-XCD ping-pong, 4x smaller memset than 64B pad.
// xpair: u32 xpair[node][20] = {f16 hi(x) (lo), f16 residual (hi)}.
__global__ __launch_bounds__(256) void bucket_mlp(
    const int* __restrict__ ei,
    const float* __restrict__ x,
    const float* __restrict__ Wpre,  const float* __restrict__ bpre,
    const float* __restrict__ Wpost, const float* __restrict__ bpost,
    const float* __restrict__ Wsc,   const float* __restrict__ bsc,
    int* __restrict__ cnt_pad,       // [NPART * N_NODES * CPAD]
    int* __restrict__ ovf_cnt,       // [1]
    int* __restrict__ ovf,           // [N_EDGES] (exact)
    uint16_t* __restrict__ bucket16, // [N_NODES * SLOTS] holds ROW (u16)
    uint32_t* __restrict__ xpair,    // [N_NODES*IN_DIM]
    float* __restrict__ out)
{
    if ((int)blockIdx.x >= MLP_BLOCKS) {
        // ---------------- edge part ----------------
        const int e = (int)((blockIdx.x - MLP_BLOCKS) * 256 + threadIdx.x);
        if (e >= N_EDGES) return;
        const int p = (int)(blockIdx.x & (NPART - 1));   // block's own XCD parity
        const int row = ei[e];
        const int col = ei[N_EDGES + e];
        const int slot = atomicAdd(&cnt_pad[((size_t)(p * N_NODES + col)) * CPAD], 1);
        if (slot >= CAP_P) { ovf[atomicAdd(ovf_cnt, 1)] = e; return; }
        bucket16[col * SLOTS + (p << 4) + slot] = (uint16_t)row;
        return;
    }

    // ---------------- MLP part: thread per node ----------------
    __shared__ float smw[1260];   // 3x400 weights + 60 biases
    for (int t = (int)threadIdx.x; t < 400; t += 256) {
        smw[t]       = Wpre[t];
        smw[400 + t] = Wpost[t];
        smw[800 + t] = Wsc[t];
    }
    if (threadIdx.x < IN_DIM) {
        smw[1200 + threadIdx.x]              = bpre[threadIdx.x];
        smw[1200 + IN_DIM + threadIdx.x]     = bpost[threadIdx.x];
        smw[1200 + 2 * IN_DIM + threadIdx.x] = bsc[threadIdx.x];
    }
    __syncthreads();

    const int i = (int)(blockIdx.x * 256 + threadIdx.x);
    if (i >= N_NODES) return;

    const float* sWpre  = smw;
    const float* sWpost = smw + 400;
    const float* sWsc   = smw + 800;
    const float* sb     = smw + 1200;

    float xi[IN_DIM], h[IN_DIM];
#pragma unroll
    for (int j = 0; j < IN_DIM; ++j) xi[j] = x[(size_t)i * IN_DIM + j];

    // compensated f16 pair for the gather kernel's MFMA A-operand
#pragma unroll
    for (int j = 0; j < IN_DIM; ++j) {
        const float v = xi[j];
        const _Float16 hh = (_Float16)v;
        const float res = v - (float)hh;
        union { _Float16 f[2]; uint32_t u; } t;
        t.f[0] = hh; t.f[1] = (_Float16)res;
        xpair[(size_t)i * IN_DIM + j] = t.u;
    }

#pragma unroll
    for (int j = 0; j < IN_DIM; ++j) {
        float a = sb[j];
#pragma unroll
        for (int kk = 0; kk < IN_DIM; ++kk) a = fmaf(xi[kk], sWpre[j * IN_DIM + kk], a);
        h[j] = fmaxf(a, 0.0f);
    }
#pragma unroll
    for (int j = 0; j < IN_DIM; ++j) {
        float a = sb[IN_DIM + j] + sb[2 * IN_DIM + j];
#pragma unroll
        for (int kk = 0; kk < IN_DIM; ++kk) {
            a = fmaf(h[kk],  sWpost[j * IN_DIM + kk], a);
            a = fmaf(xi[kk], sWsc[j * IN_DIM + kk],  a);
        }
        out[(size_t)i * OUT_DIM + j] = a;
    }
}

// -------- gather: one wave per node; SH computed in-kernel (1 edge/lane), --------
// -------- LDS transpose, then 16-edge blocks via v_mfma_f32_32x32x16_f16  --------
// C[row=feature i][col=sh comp k] = sum_e s_e[i]*sh_e[k]; col 16 = ones => sender sums.
// Lane -> packed slot m = 16*p + s via in-register prefix over the 8 partition
// counts. ALL random-access work predicated to valid lanes (R9's measured win).
// C/D layout per m74/m101: col=lane&31, row=(reg&3)+8*(reg>>2)+4*(lane>>5).
__global__ __launch_bounds__(256) void node_gather(
    const float* __restrict__ x,
    const float* __restrict__ pos,
    const int* __restrict__ ei,
    const int* __restrict__ cnt_pad,
    const uint16_t* __restrict__ bucket16,
    const uint32_t* __restrict__ xpair,
    const int* __restrict__ ovf_cnt,
    const int* __restrict__ ovf,
    float* __restrict__ out)
{
    __shared__ uint16_t shls[4][64][16];   // 8 KB: per-wave SH transpose buffer

    const int lane  = (int)(threadIdx.x & 63);
    const int w     = (int)(threadIdx.x >> 6);
    const int node  = __builtin_amdgcn_readfirstlane(
        (int)((blockIdx.x * blockDim.x + threadIdx.x) >> 6));   // grid exact
    const int col   = lane & 31;
    const int hi    = lane >> 5;
    const int khalf = hi * 8;
    const int rowc  = min(col, IN_DIM - 1);

    // ---- read 8 partition counts, build prefix + lane->slot mapping ----
    int ovf_any = 0;
    int c[NPART];
#pragma unroll
    for (int q = 0; q < NPART; ++q) {
        const int cr = __builtin_amdgcn_readfirstlane(
            cnt_pad[((size_t)(q * N_NODES + node)) * CPAD]);
        ovf_any |= (cr > CAP_P);
        c[q] = min(cr, CAP_P);
    }
    int pre = 0, pp = 0, base = 0;
#pragma unroll
    for (int q = 0; q < NPART; ++q) {
        if (q >= 1) {
            const int ge = (lane >= pre) ? 1 : 0;
            pp  += ge;
            base = ge ? pre : base;
        }
        pre += c[q];
    }
    const int cnt = min(pre, 64);                  // in-degree <= 64 in practice
    const int s  = min(lane - base, CAP_P - 1);
    const int m  = (pp << 4) + s;                  // packed slot for edge-index 'lane'

    // ---- per-lane edge (ONLY valid lanes issue memory traffic) ----
    int rl = 0;
    if (lane < cnt) {
        rl = (int)bucket16[node * SLOTS + m];   // valid lanes map to written slots
        const float rx = pos[node * 3 + 0] - pos[rl * 3 + 0];
        const float ry = pos[node * 3 + 1] - pos[rl * 3 + 1];
        const float rz = pos[node * 3 + 2] - pos[rl * 3 + 2];
        const float rinv = rsqrtf(rx * rx + ry * ry + rz * rz + EPS_F);
        const float xx = rx * rinv, yy = ry * rinv, zz = rz * rinv;
        const float x2 = xx * xx, y2 = yy * yy, z2 = zz * zz;

        const float sh0  = 0.28209479177387814f;
        const float sh1  = 0.4886025119029199f * yy;
        const float sh2  = 0.4886025119029199f * zz;
        const float sh3  = 0.4886025119029199f * xx;
        const float sh4  = 1.0925484305920792f * xx * yy;
        const float sh5  = 1.0925484305920792f * yy * zz;
        const float sh6  = 0.31539156525252005f * (3.0f * z2 - 1.0f);
        const float sh7  = 1.0925484305920792f * xx * zz;
        const float sh8  = 0.5462742152960396f * (x2 - y2);
        const float sh9  = 0.5900435899266435f * yy * (3.0f * x2 - y2);
        const float sh10 = 2.890611442640554f  * xx * yy * zz;
        const float sh11 = 0.4570457994644658f * yy * (5.0f * z2 - 1.0f);
        const float sh12 = 0.3731763325901154f * zz * (5.0f * z2 - 3.0f);
        const float sh13 = 0.4570457994644658f * xx * (5.0f * z2 - 1.0f);
        const float sh14 = 1.445305721320277f  * zz * (x2 - y2);
        const float sh15 = 0.5900435899266435f * xx * (x2 - 3.0f * y2);

        const half8 v0 = { (_Float16)sh0,  (_Float16)sh1,  (_Float16)sh2,  (_Float16)sh3,
                           (_Float16)sh4,  (_Float16)sh5,  (_Float16)sh6,  (_Float16)sh7 };
        const half8 v1 = { (_Float16)sh8,  (_Float16)sh9,  (_Float16)sh10, (_Float16)sh11,
                           (_Float16)sh12, (_Float16)sh13, (_Float16)sh14, (_Float16)sh15 };
        half8* wp = (half8*)&shls[w][lane][0];
        wp[0] = v0;
        wp[1] = v1;
    }
    // no __syncthreads(): shls[w] is wave-private; LDS is wave-synchronous.
    // Rows >= cnt stay uninitialized — they only feed tail-masked B halves.

    floatx16 acc = {0,0,0,0,0,0,0,0,0,0,0,0,0,0,0,0};

    if (cnt > 0) {
        const int nb = (cnt + 15) >> 4;
        for (int b = 0; b < nb; ++b) {
            const int sbase = 16 * b + khalf;

            int rr[8];
#pragma unroll
            for (int j = 0; j < 8; ++j)
                rr[j] = __shfl(rl, sbase + j, 64);

            // A-rows 20..31 never reach the output; skip their loads too.
            uint32_t ee[8];
#pragma unroll
            for (int j = 0; j < 8; ++j)
                ee[j] = (sbase + j < cnt && col < IN_DIM)
                      ? xpair[(size_t)rr[j] * IN_DIM + rowc] : 0u;

            // B source: LDS transpose read — comp 'col' of edges sbase+0..7
            uint32_t B0, B1, B2, B3;
            if (col < 16) {
                const uint32_t h0 = shls[w][sbase + 0][col];
                const uint32_t h1 = shls[w][sbase + 1][col];
                const uint32_t h2 = shls[w][sbase + 2][col];
                const uint32_t h3 = shls[w][sbase + 3][col];
                const uint32_t h4 = shls[w][sbase + 4][col];
                const uint32_t h5 = shls[w][sbase + 5][col];
                const uint32_t h6 = shls[w][sbase + 6][col];
                const uint32_t h7 = shls[w][sbase + 7][col];
                B0 = h0 | (h1 << 16);
                B1 = h2 | (h3 << 16);
                B2 = h4 | (h5 << 16);
                B3 = h6 | (h7 << 16);
            } else if (col == 16) {          // ones column -> sender sums
                B0 = B1 = B2 = B3 = 0x3C003C00u;
            } else {
                B0 = B1 = B2 = B3 = 0u;
            }
            const int rem = cnt - 16 * b;
            if (rem < 16) {                  // zero invalid edges (bit-level, NaN-safe)
                const int t = rem - khalf;
                B0 &= maskpair(t, 0);
                B1 &= maskpair(t, 2);
                B2 &= maskpair(t, 4);
                B3 &= maskpair(t, 6);
            }

            // A fragments: hi halves -> A1, residual halves -> A2
            uint32_t a1u[4], a2u[4];
#pragma unroll
            for (int pq = 0; pq < 4; ++pq) {
                a1u[pq] = (ee[2 * pq] & 0xFFFFu)  | (ee[2 * pq + 1] << 16);
                a2u[pq] = (ee[2 * pq] >> 16)      | (ee[2 * pq + 1] & 0xFFFF0000u);
            }

            const half8 hb  = h8_from_u32(B0, B1, B2, B3);
            const half8 ha1 = h8_from_u32(a1u[0], a1u[1], a1u[2], a1u[3]);
            const half8 ha2 = h8_from_u32(a2u[0], a2u[1], a2u[2], a2u[3]);
            acc = __builtin_amdgcn_mfma_f32_32x32x16_f16(ha1, hb, acc, 0, 0, 0);
            acc = __builtin_amdgcn_mfma_f32_32x32x16_f16(ha2, hb, acc, 0, 0, 0);
        }
    }

    // exact overflow fallback (any partition count > CAP_P; ~never taken; cold)
    if (ovf_any)
        acc = ovf_accum(acc, node, col, hi, x, pos, ei, ovf_cnt, ovf);

    // epilogue: C -> out (also writes zeros for cnt==0 nodes)
    float* orow = out + (size_t)node * OUT_DIM;
    if (col < 16) {
#pragma unroll
        for (int r = 0; r < 16; ++r) {
            const int rw = ((r & 3) + 8 * (r >> 2)) + 4 * hi;
            if (rw < IN_DIM) orow[2 * IN_DIM + rw * 16 + col] = acc[r];  // tp block
        }
    } else if (col == 16) {
#pragma unroll
        for (int r = 0; r < 16; ++r) {
            const int rw = ((r & 3) + 8 * (r >> 2)) + 4 * hi;
            if (rw < IN_DIM) orow[IN_DIM + rw] = acc[r];                 // sender sums
        }
    }
}

extern "C" void kernel_launch(void* const* d_in, const int* in_sizes, int n_in,
                              void* d_out, int out_size, void* d_ws, size_t ws_size,
                              hipStream_t stream)
{
    const float* x     = (const float*)d_in[0];
    const float* pos   = (const float*)d_in[1];
    const int*   ei    = (const int*)d_in[2];
    const float* Wpre  = (const float*)d_in[3];
    const float* bpre  = (const float*)d_in[4];
    const float* Wpost = (const float*)d_in[5];
    const float* bpost = (const float*)d_in[6];
    const float* Wsc   = (const float*)d_in[7];
    const float* bsc   = (const float*)d_in[8];
    float* out = (float*)d_out;

    // ws layout:
    //   bucket16: N*SLOTS*2B     =  5,120,000
    //   xpair   : N*20*4B        =  1,600,000
    //   cnt_pad : 8*N*CPAD*4B    =  2,560,000
    //   ovf_cnt : 4
    //   ovf     : E*4B           =    960,000
    char* wp = (char*)d_ws;
    uint16_t* bucket16 = (uint16_t*)wp;   wp += (size_t)N_NODES * SLOTS * 2;
    uint32_t* xpair    = (uint32_t*)wp;   wp += (size_t)N_NODES * IN_DIM * 4;
    int*      cnt_pad  = (int*)wp;        wp += (size_t)NPART * N_NODES * CPAD * 4;
    int*      ovf_cnt  = (int*)wp;        wp += 4;
    int*      ovf      = (int*)wp;

    // zero counters (+ ovf_cnt, adjacent) — 2.56 MB
    hipMemsetAsync(cnt_pad, 0, (size_t)NPART * N_NODES * CPAD * 4 + 4, stream);

    bucket_mlp<<<EDGE_BLOCKS + MLP_BLOCKS, 256, 0, stream>>>(
        ei, x, Wpre, bpre, Wpost, bpost, Wsc, bsc,
        cnt_pad, ovf_cnt, ovf, bucket16, xpair, out);

    node_gather<<<(N_NODES * 64) / 256, 256, 0, stream>>>(   // exactly 5000 blocks
        x, pos, ei, cnt_pad, bucket16, xpair, ovf_cnt, ovf, out);
}

// Round 12
// 112.616 us; speedup vs baseline: 1.0493x; 1.0209x over previous
//
#include <hip/hip_runtime.h>
#include <stdint.h>

#define N_NODES 20000
#define N_EDGES 240000
#define IN_DIM  20
#define OUT_DIM 360   // 20 mlp + 20 sender-sum + 320 tp
#define EPS_F   1e-12f
#define NPART   8     // counter partitions (~XCDs via blockIdx&7)
#define CAP_P   16    // slots per (node, partition); per-part count ~Poisson(1.5)
#define SLOTS   (NPART * CAP_P)   // 128 slots per node
#define CPAD    4     // counter stride in ints (16B): 4 same-partition counters/64B line
#define EPT     4     // edges per thread in k1 (ILP depth)
#define EDGE_BLOCKS ((N_EDGES + 256 * EPT - 1) / (256 * EPT))   // 235
#define MLP_BLOCKS  ((N_NODES + 255) / 256)                     // 79

typedef _Float16 half8   __attribute__((ext_vector_type(8)));
typedef float    floatx16 __attribute__((ext_vector_type(16)));
typedef int      int4v   __attribute__((ext_vector_type(4)));

__device__ __forceinline__ half8 h8_from_u32(uint32_t u0, uint32_t u1,
                                             uint32_t u2, uint32_t u3) {
    union { uint32_t u[4]; half8 h; } t;
    t.u[0] = u0; t.u[1] = u1; t.u[2] = u2; t.u[3] = u3;
    return t.h;
}

// tail-mask for B fragment: halves j, j+1 valid iff j < t
__device__ __forceinline__ uint32_t maskpair(int t, int j) {
    return (t > j ? 0xFFFFu : 0u) | (t > j + 1 ? 0xFFFF0000u : 0u);
}

// used only in the (normally never-taken) overflow path
__device__ float sh_coeff(int k, float xn, float yn, float zn) {
    const float x2 = xn * xn, y2 = yn * yn, z2 = zn * zn;
    switch (k) {
        case 0:  return 0.28209479177387814f;
        case 1:  return 0.4886025119029199f * yn;
        case 2:  return 0.4886025119029199f * zn;
        case 3:  return 0.4886025119029199f * xn;
        case 4:  return 1.0925484305920792f * xn * yn;
        case 5:  return 1.0925484305920792f * yn * zn;
        case 6:  return 0.31539156525252005f * (3.0f * z2 - 1.0f);
        case 7:  return 1.0925484305920792f * xn * zn;
        case 8:  return 0.5462742152960396f * (x2 - y2);
        case 9:  return 0.5900435899266435f * yn * (3.0f * x2 - y2);
        case 10: return 2.890611442640554f  * xn * yn * zn;
        case 11: return 0.4570457994644658f * yn * (5.0f * z2 - 1.0f);
        case 12: return 0.3731763325901154f * zn * (5.0f * z2 - 3.0f);
        case 13: return 0.4570457994644658f * xn * (5.0f * z2 - 1.0f);
        case 14: return 1.445305721320277f  * zn * (x2 - y2);
        default: return 0.5900435899266435f * xn * (x2 - 3.0f * y2); // k==15
    }
}

// cold, ~never-executed overflow accumulation — OUTLINED so the hot gather
// path's register allocation doesn't pay for it.
__device__ __noinline__ floatx16 ovf_accum(floatx16 acc, int node, int col, int hi,
    const float* __restrict__ x, const float* __restrict__ pos,
    const int* __restrict__ ei, const int* __restrict__ ovf_cnt,
    const int* __restrict__ ovf)
{
    const int mm = *ovf_cnt;
    for (int t2 = 0; t2 < mm; ++t2) {
        const int e = ovf[t2];
        if (ei[N_EDGES + e] != node) continue;   // wave-uniform
        const int row = ei[e];
        const float rx = pos[node * 3 + 0] - pos[row * 3 + 0];
        const float ry = pos[node * 3 + 1] - pos[row * 3 + 1];
        const float rz = pos[node * 3 + 2] - pos[row * 3 + 2];
        const float rinv = rsqrtf(rx * rx + ry * ry + rz * rz + EPS_F);
        float shc;
        if (col < 16)       shc = sh_coeff(col, rx * rinv, ry * rinv, rz * rinv);
        else if (col == 16) shc = 1.0f;
        else                shc = 0.0f;
#pragma unroll
        for (int r = 0; r < 16; ++r) {
            const int rw = ((r & 3) + 8 * (r >> 2)) + 4 * hi;
            if (rw < IN_DIM)
                acc[r] = fmaf(x[(size_t)row * IN_DIM + rw], shc, acc[r]);
        }
    }
    return acc;
}

// ------- fused: node MLP (blocks 0..78, FIRST so it hides under the atomic flood)
// -------        || bucket build (blocks 79.., EPT=4 edges/thread for atomic ILP) -------
// Edge part per thread: 2x dwordx4 coalesced loads, 4 independent atomics, 4x2B stores.
// 4x outstanding atomics per wave + 4x fewer waves vs 1-edge/thread (latency-bound ILP).
// Counters at 16B stride, partitioned by blockIdx&7 (same-partition 64B lines only).
// xpair: u32 xpair[node][20] = {f16 hi(x) (lo), f16 residual (hi)}.
__global__ __launch_bounds__(256) void bucket_mlp(
    const int* __restrict__ ei,
    const float* __restrict__ x,
    const float* __restrict__ Wpre,  const float* __restrict__ bpre,
    const float* __restrict__ Wpost, const float* __restrict__ bpost,
    const float* __restrict__ Wsc,   const float* __restrict__ bsc,
    int* __restrict__ cnt_pad,       // [NPART * N_NODES * CPAD]
    int* __restrict__ ovf_cnt,       // [1]
    int* __restrict__ ovf,           // [N_EDGES] (exact)
    uint16_t* __restrict__ bucket16, // [N_NODES * SLOTS] holds ROW (u16)
    uint32_t* __restrict__ xpair,    // [N_NODES*IN_DIM]
    float* __restrict__ out)
{
    if ((int)blockIdx.x >= MLP_BLOCKS) {
        // ---------------- edge part: 4 edges per thread ----------------
        const int e0 = (int)(((blockIdx.x - MLP_BLOCKS) * 256 + threadIdx.x) * EPT);
        if (e0 >= N_EDGES) return;
        const int p = (int)(blockIdx.x & (NPART - 1));   // block's own XCD parity

        if (e0 + EPT <= N_EDGES) {                        // full quad (common case)
            const int4v rows = *(const int4v*)&ei[e0];
            const int4v cols = *(const int4v*)&ei[N_EDGES + e0];
#pragma unroll
            for (int k = 0; k < EPT; ++k) {
                const int col = cols[k];
                const int slot =
                    atomicAdd(&cnt_pad[((size_t)(p * N_NODES + col)) * CPAD], 1);
                if (slot >= CAP_P) { ovf[atomicAdd(ovf_cnt, 1)] = e0 + k; continue; }
                bucket16[col * SLOTS + (p << 4) + slot] = (uint16_t)rows[k];
            }
        } else {                                          // ragged tail
            for (int k = 0; k < EPT && e0 + k < N_EDGES; ++k) {
                const int row = ei[e0 + k];
                const int col = ei[N_EDGES + e0 + k];
                const int slot =
                    atomicAdd(&cnt_pad[((size_t)(p * N_NODES + col)) * CPAD], 1);
                if (slot >= CAP_P) { ovf[atomicAdd(ovf_cnt, 1)] = e0 + k; continue; }
                bucket16[col * SLOTS + (p << 4) + slot] = (uint16_t)row;
            }
        }
        return;
    }

    // ---------------- MLP part: thread per node ----------------
    __shared__ float smw[1260];   // 3x400 weights + 60 biases
    for (int t = (int)threadIdx.x; t < 400; t += 256) {
        smw[t]       = Wpre[t];
        smw[400 + t] = Wpost[t];
        smw[800 + t] = Wsc[t];
    }
    if (threadIdx.x < IN_DIM) {
        smw[1200 + threadIdx.x]              = bpre[threadIdx.x];
        smw[1200 + IN_DIM + threadIdx.x]     = bpost[threadIdx.x];
        smw[1200 + 2 * IN_DIM + threadIdx.x] = bsc[threadIdx.x];
    }
    __syncthreads();

    const int i = (int)(blockIdx.x * 256 + threadIdx.x);
    if (i >= N_NODES) return;

    const float* sWpre  = smw;
    const float* sWpost = smw + 400;
    const float* sWsc   = smw + 800;
    const float* sb     = smw + 1200;

    float xi[IN_DIM], h[IN_DIM];
#pragma unroll
    for (int j = 0; j < IN_DIM; ++j) xi[j] = x[(size_t)i * IN_DIM + j];

    // compensated f16 pair for the gather kernel's MFMA A-operand
#pragma unroll
    for (int j = 0; j < IN_DIM; ++j) {
        const float v = xi[j];
        const _Float16 hh = (_Float16)v;
        const float res = v - (float)hh;
        union { _Float16 f[2]; uint32_t u; } t;
        t.f[0] = hh; t.f[1] = (_Float16)res;
        xpair[(size_t)i * IN_DIM + j] = t.u;
    }

#pragma unroll
    for (int j = 0; j < IN_DIM; ++j) {
        float a = sb[j];
#pragma unroll
        for (int kk = 0; kk < IN_DIM; ++kk) a = fmaf(xi[kk], sWpre[j * IN_DIM + kk], a);
        h[j] = fmaxf(a, 0.0f);
    }
#pragma unroll
    for (int j = 0; j < IN_DIM; ++j) {
        float a = sb[IN_DIM + j] + sb[2 * IN_DIM + j];
#pragma unroll
        for (int kk = 0; kk < IN_DIM; ++kk) {
            a = fmaf(h[kk],  sWpost[j * IN_DIM + kk], a);
            a = fmaf(xi[kk], sWsc[j * IN_DIM + kk],  a);
        }
        out[(size_t)i * OUT_DIM + j] = a;
    }
}

// -------- gather: one wave per node; SH computed in-kernel (1 edge/lane), --------
// -------- LDS transpose, then 16-edge blocks via v_mfma_f32_32x32x16_f16  --------
// C[row=feature i][col=sh comp k] = sum_e s_e[i]*sh_e[k]; col 16 = ones => sender sums.
// Lane -> packed slot m = 16*p + s via in-register prefix over the 8 partition
// counts. ALL random-access work predicated to valid lanes (R9's measured win).
// C/D layout per m74/m101: col=lane&31, row=(reg&3)+8*(reg>>2)+4*(lane>>5).
__global__ __launch_bounds__(256) void node_gather(
    const float* __restrict__ x,
    const float* __restrict__ pos,
    const int* __restrict__ ei,
    const int* __restrict__ cnt_pad,
    const uint16_t* __restrict__ bucket16,
    const uint32_t* __restrict__ xpair,
    const int* __restrict__ ovf_cnt,
    const int* __restrict__ ovf,
    float* __restrict__ out)
{
    __shared__ uint16_t shls[4][64][16];   // 8 KB: per-wave SH transpose buffer

    const int lane  = (int)(threadIdx.x & 63);
    const int w     = (int)(threadIdx.x >> 6);
    const int node  = __builtin_amdgcn_readfirstlane(
        (int)((blockIdx.x * blockDim.x + threadIdx.x) >> 6));   // grid exact
    const int col   = lane & 31;
    const int hi    = lane >> 5;
    const int khalf = hi * 8;
    const int rowc  = min(col, IN_DIM - 1);

    // ---- read 8 partition counts, build prefix + lane->slot mapping ----
    int ovf_any = 0;
    int c[NPART];
#pragma unroll
    for (int q = 0; q < NPART; ++q) {
        const int cr = __builtin_amdgcn_readfirstlane(
            cnt_pad[((size_t)(q * N_NODES + node)) * CPAD]);
        ovf_any |= (cr > CAP_P);
        c[q] = min(cr, CAP_P);
    }
    int pre = 0, pp = 0, base = 0;
#pragma unroll
    for (int q = 0; q < NPART; ++q) {
        if (q >= 1) {
            const int ge = (lane >= pre) ? 1 : 0;
            pp  += ge;
            base = ge ? pre : base;
        }
        pre += c[q];
    }
    const int cnt = min(pre, 64);                  // in-degree <= 64 in practice
    const int s  = min(lane - base, CAP_P - 1);
    const int m  = (pp << 4) + s;                  // packed slot for edge-index 'lane'

    // ---- per-lane edge (ONLY valid lanes issue memory traffic) ----
    int rl = 0;
    if (lane < cnt) {
        rl = (int)bucket16[node * SLOTS + m];   // valid lanes map to written slots
        const float rx = pos[node * 3 + 0] - pos[rl * 3 + 0];
        const float ry = pos[node * 3 + 1] - pos[rl * 3 + 1];
        const float rz = pos[node * 3 + 2] - pos[rl * 3 + 2];
        const float rinv = rsqrtf(rx * rx + ry * ry + rz * rz + EPS_F);
        const float xx = rx * rinv, yy = ry * rinv, zz = rz * rinv;
        const float x2 = xx * xx, y2 = yy * yy, z2 = zz * zz;

        const float sh0  = 0.28209479177387814f;
        const float sh1  = 0.4886025119029199f * yy;
        const float sh2  = 0.4886025119029199f * zz;
        const float sh3  = 0.4886025119029199f * xx;
        const float sh4  = 1.0925484305920792f * xx * yy;
        const float sh5  = 1.0925484305920792f * yy * zz;
        const float sh6  = 0.31539156525252005f * (3.0f * z2 - 1.0f);
        const float sh7  = 1.0925484305920792f * xx * zz;
        const float sh8  = 0.5462742152960396f * (x2 - y2);
        const float sh9  = 0.5900435899266435f * yy * (3.0f * x2 - y2);
        const float sh10 = 2.890611442640554f  * xx * yy * zz;
        const float sh11 = 0.4570457994644658f * yy * (5.0f * z2 - 1.0f);
        const float sh12 = 0.3731763325901154f * zz * (5.0f * z2 - 3.0f);
        const float sh13 = 0.4570457994644658f * xx * (5.0f * z2 - 1.0f);
        const float sh14 = 1.445305721320277f  * zz * (x2 - y2);
        const float sh15 = 0.5900435899266435f * xx * (x2 - 3.0f * y2);

        const half8 v0 = { (_Float16)sh0,  (_Float16)sh1,  (_Float16)sh2,  (_Float16)sh3,
                           (_Float16)sh4,  (_Float16)sh5,  (_Float16)sh6,  (_Float16)sh7 };
        const half8 v1 = { (_Float16)sh8,  (_Float16)sh9,  (_Float16)sh10, (_Float16)sh11,
                           (_Float16)sh12, (_Float16)sh13, (_Float16)sh14, (_Float16)sh15 };
        half8* wp = (half8*)&shls[w][lane][0];
        wp[0] = v0;
        wp[1] = v1;
    }
    // no __syncthreads(): shls[w] is wave-private; LDS is wave-synchronous.
    // Rows >= cnt stay uninitialized — they only feed tail-masked B halves.

    floatx16 acc = {0,0,0,0,0,0,0,0,0,0,0,0,0,0,0,0};

    if (cnt > 0) {
        const int nb = (cnt + 15) >> 4;
        for (int b = 0; b < nb; ++b) {
            const int sbase = 16 * b + khalf;

            int rr[8];
#pragma unroll
            for (int j = 0; j < 8; ++j)
                rr[j] = __shfl(rl, sbase + j, 64);

            // A-rows 20..31 never reach the output; skip their loads too.
            uint32_t ee[8];
#pragma unroll
            for (int j = 0; j < 8; ++j)
                ee[j] = (sbase + j < cnt && col < IN_DIM)
                      ? xpair[(size_t)rr[j] * IN_DIM + rowc] : 0u;

            // B source: LDS transpose read — comp 'col' of edges sbase+0..7
            uint32_t B0, B1, B2, B3;
            if (col < 16) {
                const uint32_t h0 = shls[w][sbase + 0][col];
                const uint32_t h1 = shls[w][sbase + 1][col];
                const uint32_t h2 = shls[w][sbase + 2][col];
                const uint32_t h3 = shls[w][sbase + 3][col];
                const uint32_t h4 = shls[w][sbase + 4][col];
                const uint32_t h5 = shls[w][sbase + 5][col];
                const uint32_t h6 = shls[w][sbase + 6][col];
                const uint32_t h7 = shls[w][sbase + 7][col];
                B0 = h0 | (h1 << 16);
                B1 = h2 | (h3 << 16);
                B2 = h4 | (h5 << 16);
                B3 = h6 | (h7 << 16);
            } else if (col == 16) {          // ones column -> sender sums
                B0 = B1 = B2 = B3 = 0x3C003C00u;
            } else {
                B0 = B1 = B2 = B3 = 0u;
            }
            const int rem = cnt - 16 * b;
            if (rem < 16) {                  // zero invalid edges (bit-level, NaN-safe)
                const int t = rem - khalf;
                B0 &= maskpair(t, 0);
                B1 &= maskpair(t, 2);
                B2 &= maskpair(t, 4);
                B3 &= maskpair(t, 6);
            }

            // A fragments: hi halves -> A1, residual halves -> A2
            uint32_t a1u[4], a2u[4];
#pragma unroll
            for (int pq = 0; pq < 4; ++pq) {
                a1u[pq] = (ee[2 * pq] & 0xFFFFu)  | (ee[2 * pq + 1] << 16);
                a2u[pq] = (ee[2 * pq] >> 16)      | (ee[2 * pq + 1] & 0xFFFF0000u);
            }

            const half8 hb  = h8_from_u32(B0, B1, B2, B3);
            const half8 ha1 = h8_from_u32(a1u[0], a1u[1], a1u[2], a1u[3]);
            const half8 ha2 = h8_from_u32(a2u[0], a2u[1], a2u[2], a2u[3]);
            acc = __builtin_amdgcn_mfma_f32_32x32x16_f16(ha1, hb, acc, 0, 0, 0);
            acc = __builtin_amdgcn_mfma_f32_32x32x16_f16(ha2, hb, acc, 0, 0, 0);
        }
    }

    // exact overflow fallback (any partition count > CAP_P; ~never taken; cold)
    if (ovf_any)
        acc = ovf_accum(acc, node, col, hi, x, pos, ei, ovf_cnt, ovf);

    // epilogue: C -> out (also writes zeros for cnt==0 nodes)
    float* orow = out + (size_t)node * OUT_DIM;
    if (col < 16) {
#pragma unroll
        for (int r = 0; r < 16; ++r) {
            const int rw = ((r & 3) + 8 * (r >> 2)) + 4 * hi;
            if (rw < IN_DIM) orow[2 * IN_DIM + rw * 16 + col] = acc[r];  // tp block
        }
    } else if (col == 16) {
#pragma unroll
        for (int r = 0; r < 16; ++r) {
            const int rw = ((r & 3) + 8 * (r >> 2)) + 4 * hi;
            if (rw < IN_DIM) orow[IN_DIM + rw] = acc[r];                 // sender sums
        }
    }
}

extern "C" void kernel_launch(void* const* d_in, const int* in_sizes, int n_in,
                              void* d_out, int out_size, void* d_ws, size_t ws_size,
                              hipStream_t stream)
{
    const float* x     = (const float*)d_in[0];
    const float* pos   = (const float*)d_in[1];
    const int*   ei    = (const int*)d_in[2];
    const float* Wpre  = (const float*)d_in[3];
    const float* bpre  = (const float*)d_in[4];
    const float* Wpost = (const float*)d_in[5];
    const float* bpost = (const float*)d_in[6];
    const float* Wsc   = (const float*)d_in[7];
    const float* bsc   = (const float*)d_in[8];
    float* out = (float*)d_out;

    // ws layout:
    //   bucket16: N*SLOTS*2B     =  5,120,000
    //   xpair   : N*20*4B        =  1,600,000
    //   cnt_pad : 8*N*CPAD*4B    =  2,560,000
    //   ovf_cnt : 4
    //   ovf     : E*4B           =    960,000
    char* wp = (char*)d_ws;
    uint16_t* bucket16 = (uint16_t*)wp;   wp += (size_t)N_NODES * SLOTS * 2;
    uint32_t* xpair    = (uint32_t*)wp;   wp += (size_t)N_NODES * IN_DIM * 4;
    int*      cnt_pad  = (int*)wp;        wp += (size_t)NPART * N_NODES * CPAD * 4;
    int*      ovf_cnt  = (int*)wp;        wp += 4;
    int*      ovf      = (int*)wp;

    // zero counters (+ ovf_cnt, adjacent) — 2.56 MB
    hipMemsetAsync(cnt_pad, 0, (size_t)NPART * N_NODES * CPAD * 4 + 4, stream);

    bucket_mlp<<<EDGE_BLOCKS + MLP_BLOCKS, 256, 0, stream>>>(
        ei, x, Wpre, bpre, Wpost, bpost, Wsc, bsc,
        cnt_pad, ovf_cnt, ovf, bucket16, xpair, out);

    node_gather<<<(N_NODES * 64) / 256, 256, 0, stream>>>(   // exactly 5000 blocks
        x, pos, ei, cnt_pad, bucket16, xpair, ovf_cnt, ovf, out);
}

// Round 13
// 106.294 us; speedup vs baseline: 1.1117x; 1.0595x over previous
//
#include <hip/hip_runtime.h>
#include <stdint.h>

#define N_NODES 20000
#define N_EDGES 240000
#define IN_DIM  20
#define OUT_DIM 360   // 20 mlp + 20 sender-sum + 320 tp
#define EPS_F   1e-12f
#define NPART   8     // counter partitions (~XCDs via blockIdx&7)
#define CAP_P   16    // slots per (node, partition); per-part count ~Poisson(1.5)
#define SLOTS   (NPART * CAP_P)   // 128 slots per node
#define CPAD    4     // counter stride in ints (16B): 4 same-partition counters/64B line
#define EPT     8     // edges per thread in k1 (ILP depth)
#define EDGE_BLOCKS ((N_EDGES + 256 * EPT - 1) / (256 * EPT))   // 118
#define MLP_BLOCKS  ((N_NODES + 255) / 256)                     // 79

typedef _Float16 half8   __attribute__((ext_vector_type(8)));
typedef float    floatx16 __attribute__((ext_vector_type(16)));
typedef int      int4v   __attribute__((ext_vector_type(4)));

__device__ __forceinline__ half8 h8_from_u32(uint32_t u0, uint32_t u1,
                                             uint32_t u2, uint32_t u3) {
    union { uint32_t u[4]; half8 h; } t;
    t.u[0] = u0; t.u[1] = u1; t.u[2] = u2; t.u[3] = u3;
    return t.h;
}

// tail-mask for B fragment: halves j, j+1 valid iff j < t
__device__ __forceinline__ uint32_t maskpair(int t, int j) {
    return (t > j ? 0xFFFFu : 0u) | (t > j + 1 ? 0xFFFF0000u : 0u);
}

// used only in the (normally never-taken) overflow path
__device__ float sh_coeff(int k, float xn, float yn, float zn) {
    const float x2 = xn * xn, y2 = yn * yn, z2 = zn * zn;
    switch (k) {
        case 0:  return 0.28209479177387814f;
        case 1:  return 0.4886025119029199f * yn;
        case 2:  return 0.4886025119029199f * zn;
        case 3:  return 0.4886025119029199f * xn;
        case 4:  return 1.0925484305920792f * xn * yn;
        case 5:  return 1.0925484305920792f * yn * zn;
        case 6:  return 0.31539156525252005f * (3.0f * z2 - 1.0f);
        case 7:  return 1.0925484305920792f * xn * zn;
        case 8:  return 0.5462742152960396f * (x2 - y2);
        case 9:  return 0.5900435899266435f * yn * (3.0f * x2 - y2);
        case 10: return 2.890611442640554f  * xn * yn * zn;
        case 11: return 0.4570457994644658f * yn * (5.0f * z2 - 1.0f);
        case 12: return 0.3731763325901154f * zn * (5.0f * z2 - 3.0f);
        case 13: return 0.4570457994644658f * xn * (5.0f * z2 - 1.0f);
        case 14: return 1.445305721320277f  * zn * (x2 - y2);
        default: return 0.5900435899266435f * xn * (x2 - 3.0f * y2); // k==15
    }
}

// cold, ~never-executed overflow accumulation — OUTLINED so the hot gather
// path's register allocation doesn't pay for it.
__device__ __noinline__ floatx16 ovf_accum(floatx16 acc, int node, int col, int hi,
    const float* __restrict__ x, const float* __restrict__ pos,
    const int* __restrict__ ei, const int* __restrict__ ovf_cnt,
    const int* __restrict__ ovf)
{
    const int mm = *ovf_cnt;
    for (int t2 = 0; t2 < mm; ++t2) {
        const int e = ovf[t2];
        if (ei[N_EDGES + e] != node) continue;   // wave-uniform
        const int row = ei[e];
        const float rx = pos[node * 3 + 0] - pos[row * 3 + 0];
        const float ry = pos[node * 3 + 1] - pos[row * 3 + 1];
        const float rz = pos[node * 3 + 2] - pos[row * 3 + 2];
        const float rinv = rsqrtf(rx * rx + ry * ry + rz * rz + EPS_F);
        float shc;
        if (col < 16)       shc = sh_coeff(col, rx * rinv, ry * rinv, rz * rinv);
        else if (col == 16) shc = 1.0f;
        else                shc = 0.0f;
#pragma unroll
        for (int r = 0; r < 16; ++r) {
            const int rw = ((r & 3) + 8 * (r >> 2)) + 4 * hi;
            if (rw < IN_DIM)
                acc[r] = fmaf(x[(size_t)row * IN_DIM + rw], shc, acc[r]);
        }
    }
    return acc;
}

// ------- fused: node MLP (blocks 0..78, FIRST so it hides under the atomic flood)
// -------        || bucket build (blocks 79.., EPT=8 edges/thread for atomic ILP) -------
// Edge part per thread: 4x dwordx4 coalesced loads, 8 independent atomics, 8x2B stores.
// k1 is atomic-THROUGHPUT-bound (~6.5G/s measured); EPT=8 covers the residual issue-tail.
// Counters at 16B stride, partitioned by blockIdx&7 (same-partition 64B lines only).
// xpair: u32 xpair[node][20] = {f16 hi(x) (lo), f16 residual (hi)}.
__global__ __launch_bounds__(256) void bucket_mlp(
    const int* __restrict__ ei,
    const float* __restrict__ x,
    const float* __restrict__ Wpre,  const float* __restrict__ bpre,
    const float* __restrict__ Wpost, const float* __restrict__ bpost,
    const float* __restrict__ Wsc,   const float* __restrict__ bsc,
    int* __restrict__ cnt_pad,       // [NPART * N_NODES * CPAD]
    int* __restrict__ ovf_cnt,       // [1]
    int* __restrict__ ovf,           // [N_EDGES] (exact)
    uint16_t* __restrict__ bucket16, // [N_NODES * SLOTS] holds ROW (u16)
    uint32_t* __restrict__ xpair,    // [N_NODES*IN_DIM]
    float* __restrict__ out)
{
    if ((int)blockIdx.x >= MLP_BLOCKS) {
        // ---------------- edge part: 8 edges per thread ----------------
        const int e0 = (int)(((blockIdx.x - MLP_BLOCKS) * 256 + threadIdx.x) * EPT);
        if (e0 >= N_EDGES) return;
        const int p = (int)(blockIdx.x & (NPART - 1));   // block's own XCD parity

        if (e0 + EPT <= N_EDGES) {                        // full octet (common case)
            const int4v rows0 = *(const int4v*)&ei[e0];
            const int4v rows1 = *(const int4v*)&ei[e0 + 4];
            const int4v cols0 = *(const int4v*)&ei[N_EDGES + e0];
            const int4v cols1 = *(const int4v*)&ei[N_EDGES + e0 + 4];
#pragma unroll
            for (int k = 0; k < EPT; ++k) {
                const int col = (k < 4) ? cols0[k & 3] : cols1[k & 3];
                const int row = (k < 4) ? rows0[k & 3] : rows1[k & 3];
                const int slot =
                    atomicAdd(&cnt_pad[((size_t)(p * N_NODES + col)) * CPAD], 1);
                if (slot >= CAP_P) { ovf[atomicAdd(ovf_cnt, 1)] = e0 + k; continue; }
                bucket16[col * SLOTS + (p << 4) + slot] = (uint16_t)row;
            }
        } else {                                          // ragged tail
            for (int k = 0; k < EPT && e0 + k < N_EDGES; ++k) {
                const int row = ei[e0 + k];
                const int col = ei[N_EDGES + e0 + k];
                const int slot =
                    atomicAdd(&cnt_pad[((size_t)(p * N_NODES + col)) * CPAD], 1);
                if (slot >= CAP_P) { ovf[atomicAdd(ovf_cnt, 1)] = e0 + k; continue; }
                bucket16[col * SLOTS + (p << 4) + slot] = (uint16_t)row;
            }
        }
        return;
    }

    // ---------------- MLP part: thread per node ----------------
    __shared__ float smw[1260];   // 3x400 weights + 60 biases
    for (int t = (int)threadIdx.x; t < 400; t += 256) {
        smw[t]       = Wpre[t];
        smw[400 + t] = Wpost[t];
        smw[800 + t] = Wsc[t];
    }
    if (threadIdx.x < IN_DIM) {
        smw[1200 + threadIdx.x]              = bpre[threadIdx.x];
        smw[1200 + IN_DIM + threadIdx.x]     = bpost[threadIdx.x];
        smw[1200 + 2 * IN_DIM + threadIdx.x] = bsc[threadIdx.x];
    }
    __syncthreads();

    const int i = (int)(blockIdx.x * 256 + threadIdx.x);
    if (i >= N_NODES) return;

    const float* sWpre  = smw;
    const float* sWpost = smw + 400;
    const float* sWsc   = smw + 800;
    const float* sb     = smw + 1200;

    float xi[IN_DIM], h[IN_DIM];
#pragma unroll
    for (int j = 0; j < IN_DIM; ++j) xi[j] = x[(size_t)i * IN_DIM + j];

    // compensated f16 pair for the gather kernel's MFMA A-operand
#pragma unroll
    for (int j = 0; j < IN_DIM; ++j) {
        const float v = xi[j];
        const _Float16 hh = (_Float16)v;
        const float res = v - (float)hh;
        union { _Float16 f[2]; uint32_t u; } t;
        t.f[0] = hh; t.f[1] = (_Float16)res;
        xpair[(size_t)i * IN_DIM + j] = t.u;
    }

#pragma unroll
    for (int j = 0; j < IN_DIM; ++j) {
        float a = sb[j];
#pragma unroll
        for (int kk = 0; kk < IN_DIM; ++kk) a = fmaf(xi[kk], sWpre[j * IN_DIM + kk], a);
        h[j] = fmaxf(a, 0.0f);
    }
#pragma unroll
    for (int j = 0; j < IN_DIM; ++j) {
        float a = sb[IN_DIM + j] + sb[2 * IN_DIM + j];
#pragma unroll
        for (int kk = 0; kk < IN_DIM; ++kk) {
            a = fmaf(h[kk],  sWpost[j * IN_DIM + kk], a);
            a = fmaf(xi[kk], sWsc[j * IN_DIM + kk],  a);
        }
        out[(size_t)i * OUT_DIM + j] = a;
    }
}

// -------- gather: one wave per node; SH computed in-kernel (1 edge/lane), --------
// -------- LDS transpose, then 16-edge blocks via v_mfma_f32_32x32x16_f16  --------
// C[row=feature i][col=sh comp k] = sum_e s_e[i]*sh_e[k]; col 16 = ones => sender sums.
// Partition counts fetched by lanes 0..7 in ONE parallel load (+8 readlane) —
// replaces 8 dependent broadcast loads. Lane -> packed slot m = 16*p + s via
// in-register prefix. Random-access work predicated to valid lanes.
// C/D layout per m74/m101: col=lane&31, row=(reg&3)+8*(reg>>2)+4*(lane>>5).
__global__ __launch_bounds__(256) void node_gather(
    const float* __restrict__ x,
    const float* __restrict__ pos,
    const int* __restrict__ ei,
    const int* __restrict__ cnt_pad,
    const uint16_t* __restrict__ bucket16,
    const uint32_t* __restrict__ xpair,
    const int* __restrict__ ovf_cnt,
    const int* __restrict__ ovf,
    float* __restrict__ out)
{
    __shared__ uint16_t shls[4][64][16];   // 8 KB: per-wave SH transpose buffer

    const int lane  = (int)(threadIdx.x & 63);
    const int w     = (int)(threadIdx.x >> 6);
    const int node  = __builtin_amdgcn_readfirstlane(
        (int)((blockIdx.x * blockDim.x + threadIdx.x) >> 6));   // grid exact
    const int col   = lane & 31;
    const int hi    = lane >> 5;
    const int khalf = hi * 8;
    const int rowc  = min(col, IN_DIM - 1);

    // ---- fetch 8 partition counts in parallel (lanes 0..7), distribute ----
    int cv = 0;
    if (lane < NPART)
        cv = cnt_pad[((size_t)(lane * N_NODES + node)) * CPAD];

    int ovf_any = 0;
    int c[NPART];
#pragma unroll
    for (int q = 0; q < NPART; ++q) {
        const int cr = __builtin_amdgcn_readlane(cv, q);
        ovf_any |= (cr > CAP_P);
        c[q] = min(cr, CAP_P);
    }
    int pre = 0, pp = 0, base = 0;
#pragma unroll
    for (int q = 0; q < NPART; ++q) {
        if (q >= 1) {
            const int ge = (lane >= pre) ? 1 : 0;
            pp  += ge;
            base = ge ? pre : base;
        }
        pre += c[q];
    }
    const int cnt = min(pre, 64);                  // in-degree <= 64 in practice
    const int s  = min(lane - base, CAP_P - 1);
    const int m  = (pp << 4) + s;                  // packed slot for edge-index 'lane'

    // ---- per-lane edge (ONLY valid lanes issue memory traffic) ----
    int rl = 0;
    if (lane < cnt) {
        rl = (int)bucket16[node * SLOTS + m];   // valid lanes map to written slots
        const float rx = pos[node * 3 + 0] - pos[rl * 3 + 0];
        const float ry = pos[node * 3 + 1] - pos[rl * 3 + 1];
        const float rz = pos[node * 3 + 2] - pos[rl * 3 + 2];
        const float rinv = rsqrtf(rx * rx + ry * ry + rz * rz + EPS_F);
        const float xx = rx * rinv, yy = ry * rinv, zz = rz * rinv;
        const float x2 = xx * xx, y2 = yy * yy, z2 = zz * zz;

        const float sh0  = 0.28209479177387814f;
        const float sh1  = 0.4886025119029199f * yy;
        const float sh2  = 0.4886025119029199f * zz;
        const float sh3  = 0.4886025119029199f * xx;
        const float sh4  = 1.0925484305920792f * xx * yy;
        const float sh5  = 1.0925484305920792f * yy * zz;
        const float sh6  = 0.31539156525252005f * (3.0f * z2 - 1.0f);
        const float sh7  = 1.0925484305920792f * xx * zz;
        const float sh8  = 0.5462742152960396f * (x2 - y2);
        const float sh9  = 0.5900435899266435f * yy * (3.0f * x2 - y2);
        const float sh10 = 2.890611442640554f  * xx * yy * zz;
        const float sh11 = 0.4570457994644658f * yy * (5.0f * z2 - 1.0f);
        const float sh12 = 0.3731763325901154f * zz * (5.0f * z2 - 3.0f);
        const float sh13 = 0.4570457994644658f * xx * (5.0f * z2 - 1.0f);
        const float sh14 = 1.445305721320277f  * zz * (x2 - y2);
        const float sh15 = 0.5900435899266435f * xx * (x2 - 3.0f * y2);

        const half8 v0 = { (_Float16)sh0,  (_Float16)sh1,  (_Float16)sh2,  (_Float16)sh3,
                           (_Float16)sh4,  (_Float16)sh5,  (_Float16)sh6,  (_Float16)sh7 };
        const half8 v1 = { (_Float16)sh8,  (_Float16)sh9,  (_Float16)sh10, (_Float16)sh11,
                           (_Float16)sh12, (_Float16)sh13, (_Float16)sh14, (_Float16)sh15 };
        half8* wp = (half8*)&shls[w][lane][0];
        wp[0] = v0;
        wp[1] = v1;
    }
    // no __syncthreads(): shls[w] is wave-private; LDS is wave-synchronous.
    // Rows >= cnt stay uninitialized — they only feed tail-masked B halves.

    floatx16 acc = {0,0,0,0,0,0,0,0,0,0,0,0,0,0,0,0};

    if (cnt > 0) {
        const int nb = (cnt + 15) >> 4;
        for (int b = 0; b < nb; ++b) {
            const int sbase = 16 * b + khalf;

            int rr[8];
#pragma unroll
            for (int j = 0; j < 8; ++j)
                rr[j] = __shfl(rl, sbase + j, 64);

            // A-rows 20..31 never reach the output; skip their loads too.
            uint32_t ee[8];
#pragma unroll
            for (int j = 0; j < 8; ++j)
                ee[j] = (sbase + j < cnt && col < IN_DIM)
                      ? xpair[(size_t)rr[j] * IN_DIM + rowc] : 0u;

            // B source: LDS transpose read — comp 'col' of edges sbase+0..7
            uint32_t B0, B1, B2, B3;
            if (col < 16) {
                const uint32_t h0 = shls[w][sbase + 0][col];
                const uint32_t h1 = shls[w][sbase + 1][col];
                const uint32_t h2 = shls[w][sbase + 2][col];
                const uint32_t h3 = shls[w][sbase + 3][col];
                const uint32_t h4 = shls[w][sbase + 4][col];
                const uint32_t h5 = shls[w][sbase + 5][col];
                const uint32_t h6 = shls[w][sbase + 6][col];
                const uint32_t h7 = shls[w][sbase + 7][col];
                B0 = h0 | (h1 << 16);
                B1 = h2 | (h3 << 16);
                B2 = h4 | (h5 << 16);
                B3 = h6 | (h7 << 16);
            } else if (col == 16) {          // ones column -> sender sums
                B0 = B1 = B2 = B3 = 0x3C003C00u;
            } else {
                B0 = B1 = B2 = B3 = 0u;
            }
            const int rem = cnt - 16 * b;
            if (rem < 16) {                  // zero invalid edges (bit-level, NaN-safe)
                const int t = rem - khalf;
                B0 &= maskpair(t, 0);
                B1 &= maskpair(t, 2);
                B2 &= maskpair(t, 4);
                B3 &= maskpair(t, 6);
            }

            // A fragments: hi halves -> A1, residual halves -> A2
            uint32_t a1u[4], a2u[4];
#pragma unroll
            for (int pq = 0; pq < 4; ++pq) {
                a1u[pq] = (ee[2 * pq] & 0xFFFFu)  | (ee[2 * pq + 1] << 16);
                a2u[pq] = (ee[2 * pq] >> 16)      | (ee[2 * pq + 1] & 0xFFFF0000u);
            }

            const half8 hb  = h8_from_u32(B0, B1, B2, B3);
            const half8 ha1 = h8_from_u32(a1u[0], a1u[1], a1u[2], a1u[3]);
            const half8 ha2 = h8_from_u32(a2u[0], a2u[1], a2u[2], a2u[3]);
            acc = __builtin_amdgcn_mfma_f32_32x32x16_f16(ha1, hb, acc, 0, 0, 0);
            acc = __builtin_amdgcn_mfma_f32_32x32x16_f16(ha2, hb, acc, 0, 0, 0);
        }
    }

    // exact overflow fallback (any partition count > CAP_P; ~never taken; cold)
    if (ovf_any)
        acc = ovf_accum(acc, node, col, hi, x, pos, ei, ovf_cnt, ovf);

    // epilogue: C -> out (also writes zeros for cnt==0 nodes)
    float* orow = out + (size_t)node * OUT_DIM;
    if (col < 16) {
#pragma unroll
        for (int r = 0; r < 16; ++r) {
            const int rw = ((r & 3) + 8 * (r >> 2)) + 4 * hi;
            if (rw < IN_DIM) orow[2 * IN_DIM + rw * 16 + col] = acc[r];  // tp block
        }
    } else if (col == 16) {
#pragma unroll
        for (int r = 0; r < 16; ++r) {
            const int rw = ((r & 3) + 8 * (r >> 2)) + 4 * hi;
            if (rw < IN_DIM) orow[IN_DIM + rw] = acc[r];                 // sender sums
        }
    }
}

extern "C" void kernel_launch(void* const* d_in, const int* in_sizes, int n_in,
                              void* d_out, int out_size, void* d_ws, size_t ws_size,
                              hipStream_t stream)
{
    const float* x     = (const float*)d_in[0];
    const float* pos   = (const float*)d_in[1];
    const int*   ei    = (const int*)d_in[2];
    const float* Wpre  = (const float*)d_in[3];
    const float* bpre  = (const float*)d_in[4];
    const float* Wpost = (const float*)d_in[5];
    const float* bpost = (const float*)d_in[6];
    const float* Wsc   = (const float*)d_in[7];
    const float* bsc   = (const float*)d_in[8];
    float* out = (float*)d_out;

    // ws layout:
    //   bucket16: N*SLOTS*2B     =  5,120,000
    //   xpair   : N*20*4B        =  1,600,000
    //   cnt_pad : 8*N*CPAD*4B    =  2,560,000
    //   ovf_cnt : 4
    //   ovf     : E*4B           =    960,000
    char* wp = (char*)d_ws;
    uint16_t* bucket16 = (uint16_t*)wp;   wp += (size_t)N_NODES * SLOTS * 2;
    uint32_t* xpair    = (uint32_t*)wp;   wp += (size_t)N_NODES * IN_DIM * 4;
    int*      cnt_pad  = (int*)wp;        wp += (size_t)NPART * N_NODES * CPAD * 4;
    int*      ovf_cnt  = (int*)wp;        wp += 4;
    int*      ovf      = (int*)wp;

    // zero counters (+ ovf_cnt, adjacent) — 2.56 MB
    hipMemsetAsync(cnt_pad, 0, (size_t)NPART * N_NODES * CPAD * 4 + 4, stream);

    bucket_mlp<<<EDGE_BLOCKS + MLP_BLOCKS, 256, 0, stream>>>(
        ei, x, Wpre, bpre, Wpost, bpost, Wsc, bsc,
        cnt_pad, ovf_cnt, ovf, bucket16, xpair, out);

    node_gather<<<(N_NODES * 64) / 256, 256, 0, stream>>>(   // exactly 5000 blocks
        x, pos, ei, cnt_pad, bucket16, xpair, ovf_cnt, ovf, out);
}